// Round 10
// baseline (1270.310 us; speedup 1.0000x reference)
//
#include <hip/hip_runtime.h>
#include <cstddef>
#include <cstdint>

#define NH 9
#define QLD 10  // compact xu row stride in fp16

typedef _Float16 f16x8 __attribute__((ext_vector_type(8)));
typedef _Float16 f16x4 __attribute__((ext_vector_type(4)));
typedef _Float16 f16x2 __attribute__((ext_vector_type(2)));
typedef float f32x4 __attribute__((ext_vector_type(4)));

static const int cN1 = 100000, cN2 = 25000, cN3 = 6250;
static const int cE1 = 1200000, cE2 = 300000, cE3 = 75000;

static inline unsigned ceil_div(size_t a, size_t b) { return (unsigned)((a + b - 1) / b); }

// ---------------- pre-packed B panel: WT[n][Kpad] fp16, cols = [W | Wself | u] ----------------
struct PackArgs {
    const float* W[8];
    const float* c[8];
    const float* u[8];
    int K[8], OUT[8], Kpad[8], base[8];
    int total;
};

__global__ void pack_b_all(PackArgs a, _Float16* __restrict__ wt)
{
    int i = blockIdx.x * 256 + threadIdx.x;
    if (i >= a.total) return;
    int li = 0;
#pragma unroll
    for (int j = 1; j < 8; ++j) li += (i >= a.base[j]);
    int r = i - a.base[li];
    int Kp = a.Kpad[li], K = a.K[li], OUT = a.OUT[li];
    int NC = NH * OUT, NCO = NC + OUT;
    int n = r / Kp, k = r % Kp;
    float v = 0.f;
    if (k < K) {
        if (n < NC) v = a.W[li][(size_t)k * NC + n];
        else if (n < NCO) {
            const float* cv = a.c[li];
            float t[NH], m = -1e30f;
#pragma unroll
            for (int h = 0; h < NH; ++h) { t[h] = cv[h]; m = fmaxf(m, t[h]); }
            float den = 0.f;
#pragma unroll
            for (int h = 0; h < NH; ++h) { t[h] = __expf(t[h] - m); den += t[h]; }
            int o = n - NC;
            float acc = 0.f;
#pragma unroll
            for (int h = 0; h < NH; ++h) acc += t[h] * a.W[li][(size_t)k * NC + h * OUT + o];
            v = acc / den;
        } else {
            v = a.u[li][(size_t)k * NH + (n - NCO)];
        }
    }
    wt[i] = (_Float16)v;
}

// ---------------- merged f16 MFMA GEMM: C row = [ xW (NC) | x*Wself (OUT) | xu (9) | pad ] ----------------
// B pre-packed/transposed (WT [N][Kpad] fp16, zero-padded) -> conflict-free vector LDS staging.
// Optional ridx gathers A rows. xu tail also copied to compact XUH.
// Fragment layout verified numerically (fc_head2, rounds 3-9).
__global__ __launch_bounds__(256) void gemm_merged(
    const float* __restrict__ A, int lda, const int* __restrict__ ridx,
    const _Float16* __restrict__ WT, int kpad,
    _Float16* __restrict__ C, _Float16* __restrict__ xuh,
    int M, int K, int NC, int OUT)
{
    const int N = NC + OUT + NH;
    const int NCO = NC + OUT;
    const int ldc = NCO + 16;
    const int BM = 64, BN = 64, BK = 32, LK = 40;
    __shared__ _Float16 As[BM][LK];
    __shared__ _Float16 Bs[BN][LK];  // transposed: Bs[n][k]
    const int tid = threadIdx.x;
    const int row0 = blockIdx.y * BM, col0 = blockIdx.x * BN;
    const int lane = tid & 63, wv = tid >> 6;
    const int g = lane >> 4, r16 = lane & 15;
    const int wr = wv >> 1, wc = wv & 1;
    f32x4 acc[2][2] = {};
    for (int k0 = 0; k0 < K; k0 += BK) {
        // As: 64x32 halves, 8B vector writes (conflict-free), f32 source with guards
        for (int l = tid; l < 512; l += 256) {
            int r = l >> 3, c0 = (l & 7) * 4;
            int gr = row0 + r, gk = k0 + c0;
            float v0 = 0.f, v1 = 0.f, v2 = 0.f, v3 = 0.f;
            if (gr < M) {
                int ar = ridx ? ridx[gr] : gr;
                const float* ap = A + (size_t)ar * lda + gk;
                if (gk < K)     v0 = ap[0];
                if (gk + 1 < K) v1 = ap[1];
                if (gk + 2 < K) v2 = ap[2];
                if (gk + 3 < K) v3 = ap[3];
            }
            f16x4 h;
            h[0] = (_Float16)v0; h[1] = (_Float16)v1; h[2] = (_Float16)v2; h[3] = (_Float16)v3;
            *(f16x4*)&As[r][c0] = h;
        }
        // Bs: 64x32 halves, 16B coalesced read from pre-packed WT -> 16B LDS write (<=2-way)
        {
            int nn = tid >> 2, c0 = (tid & 3) * 8;
            int gn = col0 + nn, gk = k0 + c0;
            f16x8 h = {};
            if (gn < N) h = *(const f16x8*)(WT + (size_t)gn * kpad + gk);
            *(f16x8*)&Bs[nn][c0] = h;
        }
        __syncthreads();
        f16x8 af[2], bf[2];
#pragma unroll
        for (int i = 0; i < 2; ++i) af[i] = *(const f16x8*)&As[wr * 32 + i * 16 + r16][g * 8];
#pragma unroll
        for (int j = 0; j < 2; ++j) bf[j] = *(const f16x8*)&Bs[wc * 32 + j * 16 + r16][g * 8];
#pragma unroll
        for (int i = 0; i < 2; ++i)
#pragma unroll
            for (int j = 0; j < 2; ++j)
                acc[i][j] = __builtin_amdgcn_mfma_f32_16x16x32_f16(af[i], bf[j], acc[i][j], 0, 0, 0);
        __syncthreads();
    }
#pragma unroll
    for (int i = 0; i < 2; ++i)
#pragma unroll
        for (int j = 0; j < 2; ++j) {
            int gc = col0 + wc * 32 + j * 16 + r16;
            if (gc >= N) continue;
            int tcol = gc - NCO;
#pragma unroll
            for (int rr = 0; rr < 4; ++rr) {
                int gr = row0 + wr * 32 + i * 16 + g * 4 + rr;
                if (gr >= M) continue;
                _Float16 val = (_Float16)acc[i][j][rr];
                C[(size_t)gr * ldc + gc] = val;
                if (tcol >= 0) xuh[(size_t)gr * QLD + tcol] = val;
            }
        }
}

// ---------------- counting / scan / segment-fill / single-stream scatter ----------------
__global__ void count_idx(const int* __restrict__ idx, int n, int* __restrict__ cnt)
{
    int i = blockIdx.x * 256 + threadIdx.x;
    if (i < n) atomicAdd(&cnt[idx[i]], 1);
}

__global__ void count_both(const int* __restrict__ src, const int* __restrict__ dst, int E,
                           int* __restrict__ scnt, int* __restrict__ dcnt)
{
    int i = blockIdx.x * 256 + threadIdx.x;
    if (i >= E) return;
    atomicAdd(&scnt[src[i]], 1);
    atomicAdd(&dcnt[dst[i]], 1);
}

__global__ __launch_bounds__(1024) void scan1(const int* __restrict__ in, int* __restrict__ out,
                                              int* __restrict__ part, int n)
{
    __shared__ int wsum[16];
    const int tid = threadIdx.x, lane = tid & 63, wv = tid >> 6;
    int i = blockIdx.x * 1024 + tid;
    int v = (i < n) ? in[i] : 0;
    int acc = v;
#pragma unroll
    for (int off = 1; off < 64; off <<= 1) {
        int t = __shfl_up(acc, off);
        if (lane >= off) acc += t;
    }
    if (lane == 63) wsum[wv] = acc;
    __syncthreads();
    if (wv == 0 && lane < 16) {
        int s = wsum[lane];
        int a2 = s;
#pragma unroll
        for (int off = 1; off < 16; off <<= 1) {
            int t = __shfl_up(a2, off);
            if (lane >= off) a2 += t;
        }
        wsum[lane] = a2 - s;
    }
    __syncthreads();
    int ex = wsum[wv] + acc - v;
    if (i < n) out[i] = ex;
    if (part && tid == 1023) part[blockIdx.x] = ex + v;
}

__global__ void scan_add(int* __restrict__ out, const int* __restrict__ part, int n)
{
    int i = blockIdx.x * 1024 + threadIdx.x;
    if (i < n) out[i] += part[blockIdx.x];
}

__global__ void fill_src(const int* __restrict__ soffB, const int* __restrict__ scnt,
                         int* __restrict__ srcs, int n, int ebias)
{
    int i = blockIdx.x * 256 + threadIdx.x;
    if (i >= n) return;
    int b = soffB[i] - ebias, c = scnt[i];
    for (int k = 0; k < c; ++k) srcs[b + k] = i;
}

// ONE random 4B write per edge: dsts[src-pos] = dst. (pd derived later in feast_msg)
__global__ void scatter_dst(const int* __restrict__ src, const int* __restrict__ dst, int E,
                            const int* __restrict__ soffB, int* __restrict__ curs,
                            int* __restrict__ dsts, int ebias)
{
    int e = blockIdx.x * 256 + threadIdx.x;
    if (e >= E) return;
    int s = src[e];
    int ps = soffB[s] - ebias + atomicAdd(&curs[s], 1);
    dsts[ps] = dst[e];
}

// ---------------- Phase 1: per-edge q + 9-head collapse, write MSG at dst-CSR slot ----------------
// src-sorted compute (xwa row L1-hot). pd = doff[d] + (atomicAdd(curd[d]) % deg) -- the modulo
// keeps the accumulating counter valid across the 3 feast-reuses per level and graph replays.
template <int OUT>
__global__ __launch_bounds__(256) void feast_msg(
    const int* __restrict__ srcs, const int* __restrict__ dsts, int E,
    const _Float16* __restrict__ xwa, const _Float16* __restrict__ xuh,
    const float* __restrict__ cvec, const int* __restrict__ cnt,
    const int* __restrict__ doff, int* __restrict__ curd,
    _Float16* __restrict__ msg)
{
    constexpr int NC = NH * OUT, NCO = NC + OUT, LDR = NCO + 16;
    const int T = OUT / 32;
    size_t tid = (size_t)blockIdx.x * 256 + threadIdx.x;
    int e = (int)(tid / T);
    int ch = (int)(tid % T);
    if (e >= E) return;
    int s = srcs[e], d = dsts[e];
    int deg = cnt[d];
    int pd;
    if (T == 1) {
        pd = doff[d] + (atomicAdd(&curd[d], 1) % deg);
    } else {
        int lane = threadIdx.x & 63;
        int pv = 0;
        if (ch == 0) pv = doff[d] + (atomicAdd(&curd[d], 1) % deg);
        pd = __shfl(pv, (lane / T) * T);
    }
    const f16x2* us = (const f16x2*)(xwa + (size_t)s * LDR + NCO);  // xu[s], same row as xw
    const f16x2* ud = (const f16x2*)(xuh + (size_t)d * QLD);        // xu[d], L2-resident compact
    float t[NH];
    float m = -1e30f;
#pragma unroll
    for (int i = 0; i < 4; ++i) {
        f16x2 a = us[i], b = ud[i];
        t[2 * i]     = (float)a[0] - (float)b[0] + cvec[2 * i];
        t[2 * i + 1] = (float)a[1] - (float)b[1] + cvec[2 * i + 1];
    }
    t[8] = (float)us[4][0] - (float)ud[4][0] + cvec[8];
#pragma unroll
    for (int h = 0; h < NH; ++h) m = fmaxf(m, t[h]);
    float den = 0.f;
#pragma unroll
    for (int h = 0; h < NH; ++h) { t[h] = __expf(t[h] - m); den += t[h]; }
    float sc = 1.f / (den * (float)(deg + 1));

    const f16x8* xrow = (const f16x8*)(xwa + (size_t)s * LDR);
    float acc[32] = {};
#pragma unroll
    for (int h = 0; h < NH; ++h) {
        float qh = t[h] * sc;
        const f16x8* xh = xrow + h * (OUT / 8) + ch * 4;
#pragma unroll
        for (int v = 0; v < 4; ++v) {
            f16x8 x8 = xh[v];
#pragma unroll
            for (int j = 0; j < 8; ++j) acc[v * 8 + j] += qh * (float)x8[j];
        }
    }
    f16x8* mo = (f16x8*)(msg + (size_t)pd * OUT + ch * 32);
#pragma unroll
    for (int v = 0; v < 4; ++v) {
        f16x8 r;
#pragma unroll
        for (int j = 0; j < 8; ++j) r[j] = (_Float16)acc[v * 8 + j];
        mo[v] = r;
    }
}

// ---------------- Phase 2: contiguous CSR reduce + self-loop + bias + act (+fused pooling) ----------------
template <int OUT>
__global__ __launch_bounds__(256) void feast_red(
    const int* __restrict__ doff, const int* __restrict__ cnt,
    const _Float16* __restrict__ msg, const _Float16* __restrict__ xwa,
    const float* __restrict__ bias, float* __restrict__ outp,
    int n, int ldo, int col0, int act,
    const int* __restrict__ clust, float* __restrict__ pooled)
{
    constexpr int NC = NH * OUT, LDR = NC + OUT + 16;
    const int L = OUT / 8;
    size_t tid = (size_t)blockIdx.x * 256 + threadIdx.x;
    int d = (int)(tid / L);
    int p = (int)(tid % L);
    if (d >= n) return;
    int beg = doff[d], deg = cnt[d];
    int end = beg + deg;
    float acc[8] = {};
    int i = beg;
    for (; i + 2 <= end; i += 2) {
        f16x8 v0 = *(const f16x8*)(msg + (size_t)i * OUT + p * 8);
        f16x8 v1 = *(const f16x8*)(msg + (size_t)(i + 1) * OUT + p * 8);
#pragma unroll
        for (int j = 0; j < 8; ++j) acc[j] += (float)v0[j] + (float)v1[j];
    }
    if (i < end) {
        f16x8 v0 = *(const f16x8*)(msg + (size_t)i * OUT + p * 8);
#pragma unroll
        for (int j = 0; j < 8; ++j) acc[j] += (float)v0[j];
    }
    float sc = 1.f / (float)(deg + 1);
    f16x8 sv = *(const f16x8*)(xwa + (size_t)d * LDR + NC + p * 8);  // x*Wself
    float o[8];
#pragma unroll
    for (int j = 0; j < 8; ++j) {
        float v = acc[j] + (float)sv[j] * sc + bias[p * 8 + j];
        if (act) v = v > 0.f ? v : 0.1f * v;
        o[j] = v;
    }
    float4* op = (float4*)(outp + (size_t)d * ldo + col0 + p * 8);
    op[0] = make_float4(o[0], o[1], o[2], o[3]);
    op[1] = make_float4(o[4], o[5], o[6], o[7]);
    if (clust) {  // fused mean-pool accumulation
        float* pp = pooled + (size_t)clust[d] * OUT + p * 8;
#pragma unroll
        for (int j = 0; j < 8; ++j) unsafeAtomicAdd(&pp[j], o[j]);
    }
}

// ---------------- pooling divide ----------------
__global__ void pool_div(float* __restrict__ pooled, const int* __restrict__ pcnt, int C, int m)
{
    size_t tid = (size_t)blockIdx.x * 256 + threadIdx.x;
    int j = (int)(tid / C);
    if (j >= m) return;
    pooled[tid] /= fmaxf((float)pcnt[j], 1.f);
}

// ---------------- fc1 weight -> fp16 transposed [1024][32] ----------------
__global__ void w1_to_f16t(const float* __restrict__ w1, _Float16* __restrict__ w1t)
{
    int i = blockIdx.x * 256 + threadIdx.x;
    if (i >= 32 * 1024) return;
    int n = i >> 5, k = i & 31;
    w1t[i] = (_Float16)w1[k * 1024 + n];
}

// ---------------- fused FC head via f16 MFMA: lrelu(y@W1+b1)@W2+b2, row-normalize ----------------
__global__ __launch_bounds__(256) void fc_head2(
    const float* __restrict__ yin, const _Float16* __restrict__ w1t,
    const float* __restrict__ b1, const float* __restrict__ w2,
    const float* __restrict__ b2, float* __restrict__ outp, int n)
{
    const int lane = threadIdx.x & 63, wv = threadIdx.x >> 6;
    const int g = lane >> 4, r16 = lane & 15;
    const int node0 = blockIdx.x * 64 + wv * 16;

    f16x8 afrag;
    int anode = node0 + r16;
    if (anode < n) {
        const float* yr = yin + (size_t)anode * 32 + g * 8;
#pragma unroll
        for (int j = 0; j < 8; ++j) afrag[j] = (_Float16)yr[j];
    } else {
#pragma unroll
        for (int j = 0; j < 8; ++j) afrag[j] = (_Float16)0.f;
    }

    float o0[4] = {0.f, 0.f, 0.f, 0.f};
    float o1[4] = {0.f, 0.f, 0.f, 0.f};
    float o2[4] = {0.f, 0.f, 0.f, 0.f};
    const f32x4 zero4 = {0.f, 0.f, 0.f, 0.f};

#pragma unroll 2
    for (int t = 0; t < 64; ++t) {
        const f16x8 bfrag = *(const f16x8*)(w1t + ((size_t)(t * 16 + r16)) * 32 + g * 8);
        f32x4 d = __builtin_amdgcn_mfma_f32_16x16x32_f16(afrag, bfrag, zero4, 0, 0, 0);
        int kh = t * 16 + r16;
        float b1v = b1[kh];
        float w20 = w2[kh * 3], w21 = w2[kh * 3 + 1], w22 = w2[kh * 3 + 2];
#pragma unroll
        for (int r = 0; r < 4; ++r) {
            float h = d[r] + b1v;
            h = h > 0.f ? h : 0.1f * h;
            o0[r] += h * w20;
            o1[r] += h * w21;
            o2[r] += h * w22;
        }
    }
#pragma unroll
    for (int r = 0; r < 4; ++r) {
#pragma unroll
        for (int off = 1; off < 16; off <<= 1) {
            o0[r] += __shfl_xor(o0[r], off);
            o1[r] += __shfl_xor(o1[r], off);
            o2[r] += __shfl_xor(o2[r], off);
        }
    }
    if (r16 == 0) {
#pragma unroll
        for (int r = 0; r < 4; ++r) {
            int node = node0 + g * 4 + r;
            if (node >= n) continue;
            float v0 = o0[r] + b2[0];
            float v1 = o1[r] + b2[1];
            float v2 = o2[r] + b2[2];
            float nr = fmaxf(sqrtf(v0 * v0 + v1 * v1 + v2 * v2), 1e-12f);
            outp[(size_t)node * 3 + 0] = v0 / nr;
            outp[(size_t)node * 3 + 1] = v1 / nr;
            outp[(size_t)node * 3 + 2] = v2 / nr;
        }
    }
}

// ---------------- dispatch helpers ----------------
static void launch_msg(int outC, const int* srcs, const int* dsts, int E,
                       const _Float16* xwa, const _Float16* xuh, const float* cvec,
                       const int* cnt, const int* doff, int* curd,
                       _Float16* msg, hipStream_t stream)
{
    dim3 g(ceil_div((size_t)E * (outC / 32), 256));
    if (outC == 32)       feast_msg<32><<<g, 256, 0, stream>>>(srcs, dsts, E, xwa, xuh, cvec, cnt, doff, curd, msg);
    else if (outC == 64)  feast_msg<64><<<g, 256, 0, stream>>>(srcs, dsts, E, xwa, xuh, cvec, cnt, doff, curd, msg);
    else                  feast_msg<128><<<g, 256, 0, stream>>>(srcs, dsts, E, xwa, xuh, cvec, cnt, doff, curd, msg);
}

static void launch_red(int outC, const int* doff, const int* cnt,
                       const _Float16* msg, const _Float16* xwa, const float* bias,
                       float* outp, int n, int ldo, int col0, int act,
                       const int* clust, float* pooled, hipStream_t stream)
{
    dim3 g(ceil_div((size_t)n * (outC / 8), 256));
    if (outC == 32)       feast_red<32><<<g, 256, 0, stream>>>(doff, cnt, msg, xwa, bias, outp, n, ldo, col0, act, clust, pooled);
    else if (outC == 64)  feast_red<64><<<g, 256, 0, stream>>>(doff, cnt, msg, xwa, bias, outp, n, ldo, col0, act, clust, pooled);
    else                  feast_red<128><<<g, 256, 0, stream>>>(doff, cnt, msg, xwa, bias, outp, n, ldo, col0, act, clust, pooled);
}

extern "C" void kernel_launch(void* const* d_in, const int* in_sizes, int n_in,
                              void* d_out, int out_size, void* d_ws, size_t ws_size,
                              hipStream_t stream)
{
    const float* x      = (const float*)d_in[0];
    const int*   ei1    = (const int*)d_in[1];
    const int*   ei2    = (const int*)d_in[2];
    const int*   ei3    = (const int*)d_in[3];
    const int*   clust2 = (const int*)d_in[4];
    const int*   clust3 = (const int*)d_in[5];
    const float* lp[8][4];
    for (int i = 0; i < 8; ++i)
        for (int j = 0; j < 4; ++j)
            lp[i][j] = (const float*)d_in[6 + i * 4 + j];  // l1..l4,r1..r4 x {u,c,w,b}
    const float* fc1_w = (const float*)d_in[38];
    const float* fc1_b = (const float*)d_in[39];
    const float* fc2_w = (const float*)d_in[40];
    const float* fc2_b = (const float*)d_in[41];
    float* out = (float*)d_out;

    static const int lK[8]   = {6, 32, 64, 128, 128, 128, 64, 64};
    static const int lOUT[8] = {32, 64, 128, 128, 64, 64, 32, 32};

    // ---- workspace layout (~205 MB) ----
    char* ws = (char*)d_ws;
    size_t off = 0;
    auto alloc = [&](size_t b) { size_t p = off; off += (b + 255) & ~(size_t)255; return p; };
    _Float16* XWA = (_Float16*)(ws + alloc((size_t)cN1 * 336 * 2));  // 67.2 MB (max n*LDR)
    _Float16* MSG = (_Float16*)(ws + alloc((size_t)cE1 * 32 * 2));   // 76.8 MB
    _Float16* XUH = (_Float16*)(ws + alloc((size_t)cN1 * QLD * 2));  // 2 MB
    float* GATH  = (float*)(ws + alloc((size_t)cN1 * 32 * 4));       // 12.8 MB (pool scratch; YB alias)
    float* X1CAT = (float*)(ws + alloc((size_t)cN1 * 64 * 4));       // 25.6 MB
    float* X2CAT = (float*)(ws + alloc((size_t)cN2 * 128 * 4));      // 12.8 MB
    float* X2B   = (float*)(ws + alloc((size_t)cN2 * 64 * 4));       // 6.4 MB
    float* X3    = (float*)(ws + alloc((size_t)cN3 * 128 * 4));      // 3.2 MB
    int* SRCS1 = (int*)(ws + alloc((size_t)cE1 * 4));
    int* SRCS2 = (int*)(ws + alloc((size_t)cE2 * 4));
    int* SRCS3 = (int*)(ws + alloc((size_t)cE3 * 4));
    int* DSTS1 = (int*)(ws + alloc((size_t)cE1 * 4));
    int* DSTS2 = (int*)(ws + alloc((size_t)cE2 * 4));
    int* DSTS3 = (int*)(ws + alloc((size_t)cE3 * 4));
    // combined scan outputs per level: [doff(n) | soff+E(n)]
    int* DS1 = (int*)(ws + alloc((size_t)2 * cN1 * 4));
    int* DS2 = (int*)(ws + alloc((size_t)2 * cN2 * 4));
    int* DS3 = (int*)(ws + alloc((size_t)2 * cN3 * 4));
    // zero-block, ONE memset: per level [dcnt|scnt|curs|curd] + PC2 + PC3
    size_t zn = (size_t)4 * (cN1 + cN2 + cN3) + cN2 + cN3;
    int* ZBLK = (int*)(ws + alloc(zn * 4));
    int* CB1 = ZBLK;                  // dcnt1|scnt1
    int* CURS1 = CB1 + 2 * cN1;
    int* CURD1 = CURS1 + cN1;
    int* CB2 = CURD1 + cN1;
    int* CURS2 = CB2 + 2 * cN2;
    int* CURD2 = CURS2 + cN2;
    int* CB3 = CURD2 + cN2;
    int* CURS3 = CB3 + 2 * cN3;
    int* CURD3 = CURS3 + cN3;
    int* PC2 = CURD3 + cN3;
    int* PC3 = PC2 + cN2;
    int* PART = (int*)(ws + alloc(1024 * 4));
    _Float16* W1T = (_Float16*)(ws + alloc((size_t)32 * 1024 * 2));
    // pre-packed B panels
    PackArgs pa;
    int ptot = 0;
    for (int i = 0; i < 8; ++i) {
        pa.W[i] = lp[i][2]; pa.c[i] = lp[i][1]; pa.u[i] = lp[i][0];
        pa.K[i] = lK[i]; pa.OUT[i] = lOUT[i];
        pa.Kpad[i] = (lK[i] + 31) & ~31;
        pa.base[i] = ptot;
        ptot += (NH * lOUT[i] + lOUT[i] + NH) * pa.Kpad[i];
    }
    pa.total = ptot;
    _Float16* WT = (_Float16*)(ws + alloc((size_t)ptot * 2));  // ~1 MB
    float* YB = GATH;  // r4 output aliases pool scratch (free by then)

    auto run_scan = [&](const int* in, int* outp, int n) {
        int nb = (n + 1023) / 1024;
        scan1<<<nb, 1024, 0, stream>>>(in, outp, nb > 1 ? PART : nullptr, n);
        if (nb > 1) {
            scan1<<<1, 1024, 0, stream>>>(PART, PART, nullptr, nb);
            scan_add<<<nb, 1024, 0, stream>>>(outp, PART, n);
        }
    };

    // ---- zero all counters in ONE memset ----
    hipMemsetAsync(ZBLK, 0, zn * 4, stream);

    // ---- per-level build: fused counts, ONE combined scan, segment-fill, 4B scatter ----
    auto build = [&](const int* ei, int E, int n, int* cb, int* curs, int* ds,
                     int* srcs, int* dsts) {
        count_both<<<ceil_div(E, 256), 256, 0, stream>>>(ei, ei + E, E, cb + n, cb);
        run_scan(cb, ds, 2 * n);  // ds[0:n]=doff ; ds[n:2n]=soff+E
        fill_src<<<ceil_div(n, 256), 256, 0, stream>>>(ds + n, cb + n, srcs, n, E);
        scatter_dst<<<ceil_div(E, 256), 256, 0, stream>>>(ei, ei + E, E, ds + n, curs, dsts, E);
    };
    build(ei1, cE1, cN1, CB1, CURS1, DS1, SRCS1, DSTS1);
    build(ei2, cE2, cN2, CB2, CURS2, DS2, SRCS2, DSTS2);
    build(ei3, cE3, cN3, CB3, CURS3, DS3, SRCS3, DSTS3);

    // ---- pack all B panels (W|Wself|u, transposed fp16) + fc1 transpose ----
    pack_b_all<<<ceil_div(ptot, 256), 256, 0, stream>>>(pa, WT);
    w1_to_f16t<<<ceil_div(32 * 1024, 256), 256, 0, stream>>>(fc1_w, W1T);

    auto feast = [&](const float* xin, int ldx, const int* ridx, int n, int cin, int li,
                     const int* srcs, const int* dsts, const int* ds, const int* cnt,
                     int* curd, int E, float* dstp, int ldo, int col0, int act,
                     const int* pclust, float* pooled) {
        int outC = lOUT[li];
        int NC = NH * outC;
        int N = NC + outC + NH;
        gemm_merged<<<dim3(ceil_div(N, 64), ceil_div(n, 64)), 256, 0, stream>>>(
            xin, ldx, ridx, WT + (size_t)pa.base[li], pa.Kpad[li], XWA, XUH, n, cin, NC, outC);
        launch_msg(outC, srcs, dsts, E, XWA, XUH, lp[li][1], cnt, ds, curd, MSG, stream);
        launch_red(outC, ds, cnt, MSG, XWA, lp[li][3], dstp, n, ldo, col0, act, pclust, pooled, stream);
    };

    // l1: [N1,6] -> [N1,32] into X1CAT[:, 0:32]  (+fused pool into GATH)
    hipMemsetAsync(GATH, 0, (size_t)cN2 * 32 * 4, stream);
    count_idx<<<ceil_div(cN1, 256), 256, 0, stream>>>(clust2, cN1, PC2);
    feast(x, 6, nullptr, cN1, 6, 0, SRCS1, DSTS1, DS1, CB1, CURD1, cE1, X1CAT, 64, 0, 1, clust2, GATH);
    pool_div<<<ceil_div((size_t)cN2 * 32, 256), 256, 0, stream>>>(GATH, PC2, 32, cN2);

    // l2: [N2,32] -> [N2,64] into X2CAT[:, 0:64]  (+fused pool into X2B scratch)
    count_idx<<<ceil_div(cN2, 256), 256, 0, stream>>>(clust3, cN2, PC3);
    hipMemsetAsync(X2B, 0, (size_t)cN3 * 64 * 4, stream);  // pool3 target (X2B free until r2)
    feast(GATH, 32, nullptr, cN2, 32, 1, SRCS2, DSTS2, DS2, CB2, CURD2, cE2, X2CAT, 128, 0, 1, clust3, X2B);
    pool_div<<<ceil_div((size_t)cN3 * 64, 256), 256, 0, stream>>>(X2B, PC3, 64, cN3);

    // l3: [N3,64] -> [N3,128] into X3
    feast(X2B, 64, nullptr, cN3, 64, 2, SRCS3, DSTS3, DS3, CB3, CURD3, cE3, X3, 128, 0, 1, nullptr, nullptr);
    // l4: [N3,128] -> [N3,128] in-place (X3 consumed by gemm before red writes)
    feast(X3, 128, nullptr, cN3, 128, 3, SRCS3, DSTS3, DS3, CB3, CURD3, cE3, X3, 128, 0, 1, nullptr, nullptr);

    // r1: feast over unpooled x3 (gather fused via ridx=clust3) -> X2CAT[:, 64:128] (no act)
    feast(X3, 128, clust3, cN2, 128, 4, SRCS2, DSTS2, DS2, CB2, CURD2, cE2, X2CAT, 128, 64, 0, nullptr, nullptr);

    // r2: [N2,128] -> [N2,64] into X2B
    feast(X2CAT, 128, nullptr, cN2, 128, 5, SRCS2, DSTS2, DS2, CB2, CURD2, cE2, X2B, 64, 0, 1, nullptr, nullptr);

    // r3: feast over unpooled x2 (gather fused via ridx=clust2) -> X1CAT[:, 32:64] (no act)
    feast(X2B, 64, clust2, cN1, 64, 6, SRCS1, DSTS1, DS1, CB1, CURD1, cE1, X1CAT, 64, 32, 0, nullptr, nullptr);

    // r4: [N1,64] -> [N1,32] into YB
    feast(X1CAT, 64, nullptr, cN1, 64, 7, SRCS1, DSTS1, DS1, CB1, CURD1, cE1, YB, 32, 0, 1, nullptr, nullptr);

    // fused FC head + normalize (f16 MFMA)
    fc_head2<<<ceil_div(cN1, 64), 256, 0, stream>>>(YB, W1T, fc1_b, fc2_w, fc2_b, out, cN1);

    (void)in_sizes; (void)n_in; (void)out_size; (void)ws_size;
}

// Round 11
// 1108.296 us; speedup vs baseline: 1.1462x; 1.1462x over previous
//
#include <hip/hip_runtime.h>
#include <cstddef>
#include <cstdint>

#define NH 9
#define QLD 16  // compact xu row stride in fp16 (32B, line-aligned rows)

typedef _Float16 f16x8 __attribute__((ext_vector_type(8)));
typedef _Float16 f16x4 __attribute__((ext_vector_type(4)));
typedef _Float16 f16x2 __attribute__((ext_vector_type(2)));
typedef float f32x4 __attribute__((ext_vector_type(4)));

static const int cN1 = 100000, cN2 = 25000, cN3 = 6250;
static const int cE1 = 1200000, cE2 = 300000, cE3 = 75000;

static inline unsigned ceil_div(size_t a, size_t b) { return (unsigned)((a + b - 1) / b); }

// ---------------- pre-packed B panel: WT[n][Kpad] fp16, cols = [W | Wself | u] ----------------
struct PackArgs {
    const float* W[8];
    const float* c[8];
    const float* u[8];
    int K[8], OUT[8], Kpad[8], base[8];
    int total;
};

__global__ void pack_b_all(PackArgs a, _Float16* __restrict__ wt)
{
    int i = blockIdx.x * 256 + threadIdx.x;
    if (i >= a.total) return;
    int li = 0;
#pragma unroll
    for (int j = 1; j < 8; ++j) li += (i >= a.base[j]);
    int r = i - a.base[li];
    int Kp = a.Kpad[li], K = a.K[li], OUT = a.OUT[li];
    int NC = NH * OUT, NCO = NC + OUT;
    int n = r / Kp, k = r % Kp;
    float v = 0.f;
    if (k < K) {
        if (n < NC) v = a.W[li][(size_t)k * NC + n];
        else if (n < NCO) {
            const float* cv = a.c[li];
            float t[NH], m = -1e30f;
#pragma unroll
            for (int h = 0; h < NH; ++h) { t[h] = cv[h]; m = fmaxf(m, t[h]); }
            float den = 0.f;
#pragma unroll
            for (int h = 0; h < NH; ++h) { t[h] = __expf(t[h] - m); den += t[h]; }
            int o = n - NC;
            float acc = 0.f;
#pragma unroll
            for (int h = 0; h < NH; ++h) acc += t[h] * a.W[li][(size_t)k * NC + h * OUT + o];
            v = acc / den;
        } else {
            v = a.u[li][(size_t)k * NH + (n - NCO)];
        }
    }
    wt[i] = (_Float16)v;
}

// ---------------- merged f16 MFMA GEMM: C row = [ xW (NC) | x*Wself (OUT) | xu (9) | pad ] ----------------
// A is fp32 or fp16 (template); fp16 path uses direct 16B loads -> conflict-free LDS staging.
// Optional ridx gathers A rows. xu tail also copied to compact XUH.
// Fragment layout verified numerically (fc_head2, rounds 3-10).
template <typename AT>
__global__ __launch_bounds__(256) void gemm_merged(
    const AT* __restrict__ A, int lda, const int* __restrict__ ridx,
    const _Float16* __restrict__ WT, int kpad,
    _Float16* __restrict__ C, _Float16* __restrict__ xuh,
    int M, int K, int NC, int OUT)
{
    const int N = NC + OUT + NH;
    const int NCO = NC + OUT;
    const int ldc = NCO + 16;
    const int BM = 64, BK = 32, LK = 40;
    __shared__ _Float16 As[BM][LK];
    __shared__ _Float16 Bs[64][LK];  // transposed: Bs[n][k]
    const int tid = threadIdx.x;
    const int row0 = blockIdx.y * BM, col0 = blockIdx.x * 64;
    const int lane = tid & 63, wv = tid >> 6;
    const int g = lane >> 4, r16 = lane & 15;
    const int wr = wv >> 1, wc = wv & 1;
    f32x4 acc[2][2] = {};
    for (int k0 = 0; k0 < K; k0 += BK) {
        if constexpr (sizeof(AT) == 2) {
            // fp16 A: 64 rows x 4 chunks of 8 halves; K is a multiple of 32 here
            int r = tid >> 2, c0 = (tid & 3) * 8;
            int gr = row0 + r, gk = k0 + c0;
            f16x8 h = {};
            if (gr < M) {
                int ar = ridx ? ridx[gr] : gr;
                h = *(const f16x8*)((const _Float16*)A + (size_t)ar * lda + gk);
            }
            *(f16x8*)&As[r][c0] = h;
        } else {
            for (int l = tid; l < 512; l += 256) {
                int r = l >> 3, c0 = (l & 7) * 4;
                int gr = row0 + r, gk = k0 + c0;
                float v0 = 0.f, v1 = 0.f, v2 = 0.f, v3 = 0.f;
                if (gr < M) {
                    int ar = ridx ? ridx[gr] : gr;
                    const float* ap = (const float*)A + (size_t)ar * lda + gk;
                    if (gk < K)     v0 = ap[0];
                    if (gk + 1 < K) v1 = ap[1];
                    if (gk + 2 < K) v2 = ap[2];
                    if (gk + 3 < K) v3 = ap[3];
                }
                f16x4 h;
                h[0] = (_Float16)v0; h[1] = (_Float16)v1; h[2] = (_Float16)v2; h[3] = (_Float16)v3;
                *(f16x4*)&As[r][c0] = h;
            }
        }
        // Bs: 16B coalesced read from pre-packed WT -> 16B LDS write (<=2-way, free)
        {
            int nn = tid >> 2, c0 = (tid & 3) * 8;
            int gn = col0 + nn, gk = k0 + c0;
            f16x8 h = {};
            if (gn < N) h = *(const f16x8*)(WT + (size_t)gn * kpad + gk);
            *(f16x8*)&Bs[nn][c0] = h;
        }
        __syncthreads();
        f16x8 af[2], bf[2];
#pragma unroll
        for (int i = 0; i < 2; ++i) af[i] = *(const f16x8*)&As[wr * 32 + i * 16 + r16][g * 8];
#pragma unroll
        for (int j = 0; j < 2; ++j) bf[j] = *(const f16x8*)&Bs[wc * 32 + j * 16 + r16][g * 8];
#pragma unroll
        for (int i = 0; i < 2; ++i)
#pragma unroll
            for (int j = 0; j < 2; ++j)
                acc[i][j] = __builtin_amdgcn_mfma_f32_16x16x32_f16(af[i], bf[j], acc[i][j], 0, 0, 0);
        __syncthreads();
    }
#pragma unroll
    for (int i = 0; i < 2; ++i)
#pragma unroll
        for (int j = 0; j < 2; ++j) {
            int gc = col0 + wc * 32 + j * 16 + r16;
            if (gc >= N) continue;
            int tcol = gc - NCO;
#pragma unroll
            for (int rr = 0; rr < 4; ++rr) {
                int gr = row0 + wr * 32 + i * 16 + g * 4 + rr;
                if (gr >= M) continue;
                _Float16 val = (_Float16)acc[i][j][rr];
                C[(size_t)gr * ldc + gc] = val;
                if (tcol >= 0) xuh[(size_t)gr * QLD + tcol] = val;
            }
        }
}

// ---------------- counting / scan / segment-fill / single-stream scatter ----------------
__global__ void count_idx(const int* __restrict__ idx, int n, int* __restrict__ cnt)
{
    int i = blockIdx.x * 256 + threadIdx.x;
    if (i < n) atomicAdd(&cnt[idx[i]], 1);
}

__global__ void count_both(const int* __restrict__ src, const int* __restrict__ dst, int E,
                           int* __restrict__ scnt, int* __restrict__ dcnt)
{
    int i = blockIdx.x * 256 + threadIdx.x;
    if (i >= E) return;
    atomicAdd(&scnt[src[i]], 1);
    atomicAdd(&dcnt[dst[i]], 1);
}

__global__ __launch_bounds__(1024) void scan1(const int* __restrict__ in, int* __restrict__ out,
                                              int* __restrict__ part, int n)
{
    __shared__ int wsum[16];
    const int tid = threadIdx.x, lane = tid & 63, wv = tid >> 6;
    int i = blockIdx.x * 1024 + tid;
    int v = (i < n) ? in[i] : 0;
    int acc = v;
#pragma unroll
    for (int off = 1; off < 64; off <<= 1) {
        int t = __shfl_up(acc, off);
        if (lane >= off) acc += t;
    }
    if (lane == 63) wsum[wv] = acc;
    __syncthreads();
    if (wv == 0 && lane < 16) {
        int s = wsum[lane];
        int a2 = s;
#pragma unroll
        for (int off = 1; off < 16; off <<= 1) {
            int t = __shfl_up(a2, off);
            if (lane >= off) a2 += t;
        }
        wsum[lane] = a2 - s;
    }
    __syncthreads();
    int ex = wsum[wv] + acc - v;
    if (i < n) out[i] = ex;
    if (part && tid == 1023) part[blockIdx.x] = ex + v;
}

__global__ void scan_add(int* __restrict__ out, const int* __restrict__ part, int n)
{
    int i = blockIdx.x * 1024 + threadIdx.x;
    if (i < n) out[i] += part[blockIdx.x];
}

__global__ void fill_src(const int* __restrict__ soffB, const int* __restrict__ scnt,
                         int* __restrict__ srcs, int n, int ebias)
{
    int i = blockIdx.x * 256 + threadIdx.x;
    if (i >= n) return;
    int b = soffB[i] - ebias, c = scnt[i];
    for (int k = 0; k < c; ++k) srcs[b + k] = i;
}

// ONE random 4B write per edge: dsts[src-pos] = dst.
__global__ void scatter_dst(const int* __restrict__ src, const int* __restrict__ dst, int E,
                            const int* __restrict__ soffB, int* __restrict__ curs,
                            int* __restrict__ dsts, int ebias)
{
    int e = blockIdx.x * 256 + threadIdx.x;
    if (e >= E) return;
    int s = src[e];
    int ps = soffB[s] - ebias + atomicAdd(&curs[s], 1);
    dsts[ps] = dst[e];
}

// ---------------- Phase 1: per-edge q + 9-head collapse, write MSG at dst-CSR slot ----------------
// src-sorted compute (xwa row L1-hot). deg = ds[d+1]-ds[d] (sentinel ds[n]=E) -- single
// same-line load pair. pd via atomicAdd(curd[d]) % deg (valid across 3 reuses + replays).
template <int OUT>
__global__ __launch_bounds__(256) void feast_msg(
    const int* __restrict__ srcs, const int* __restrict__ dsts, int E,
    const _Float16* __restrict__ xwa, const _Float16* __restrict__ xuh,
    const float* __restrict__ cvec, const int* __restrict__ ds,
    int* __restrict__ curd, _Float16* __restrict__ msg)
{
    constexpr int NC = NH * OUT, NCO = NC + OUT, LDR = NCO + 16;
    const int T = OUT / 32;
    size_t tid = (size_t)blockIdx.x * 256 + threadIdx.x;
    int e = (int)(tid / T);
    int ch = (int)(tid % T);
    if (e >= E) return;
    int s = srcs[e], d = dsts[e];
    int beg = ds[d];
    int deg = ds[d + 1] - beg;
    int pd;
    if (T == 1) {
        pd = beg + (atomicAdd(&curd[d], 1) % deg);
    } else {
        int lane = threadIdx.x & 63;
        int pv = 0;
        if (ch == 0) pv = beg + (atomicAdd(&curd[d], 1) % deg);
        pd = __shfl(pv, (lane / T) * T);
    }
    f16x8 u8s = *(const f16x8*)(xwa + (size_t)s * LDR + NCO);
    f16x2 u2s = *(const f16x2*)(xwa + (size_t)s * LDR + NCO + 8);
    f16x8 u8d = *(const f16x8*)(xuh + (size_t)d * QLD);
    f16x2 u2d = *(const f16x2*)(xuh + (size_t)d * QLD + 8);
    float t[NH];
    float m = -1e30f;
#pragma unroll
    for (int h = 0; h < 8; ++h) {
        t[h] = (float)u8s[h] - (float)u8d[h] + cvec[h];
        m = fmaxf(m, t[h]);
    }
    t[8] = (float)u2s[0] - (float)u2d[0] + cvec[8];
    m = fmaxf(m, t[8]);
    float den = 0.f;
#pragma unroll
    for (int h = 0; h < NH; ++h) { t[h] = __expf(t[h] - m); den += t[h]; }
    float sc = 1.f / (den * (float)(deg + 1));

    const f16x8* xrow = (const f16x8*)(xwa + (size_t)s * LDR);
    float acc[32] = {};
#pragma unroll
    for (int h = 0; h < NH; ++h) {
        float qh = t[h] * sc;
        const f16x8* xh = xrow + h * (OUT / 8) + ch * 4;
#pragma unroll
        for (int v = 0; v < 4; ++v) {
            f16x8 x8 = xh[v];
#pragma unroll
            for (int j = 0; j < 8; ++j) acc[v * 8 + j] += qh * (float)x8[j];
        }
    }
    f16x8* mo = (f16x8*)(msg + (size_t)pd * OUT + ch * 32);
#pragma unroll
    for (int v = 0; v < 4; ++v) {
        f16x8 r;
#pragma unroll
        for (int j = 0; j < 8; ++j) r[j] = (_Float16)acc[v * 8 + j];
        mo[v] = r;
    }
}

// ---------------- Phase 2: contiguous CSR reduce + self-loop + bias + act, fp16 out (+fused pool) ----------------
template <int OUT>
__global__ __launch_bounds__(256) void feast_red(
    const int* __restrict__ ds,
    const _Float16* __restrict__ msg, const _Float16* __restrict__ xwa,
    const float* __restrict__ bias, _Float16* __restrict__ outp,
    int n, int ldo, int col0, int act,
    const int* __restrict__ clust, float* __restrict__ pooled)
{
    constexpr int NC = NH * OUT, LDR = NC + OUT + 16;
    const int L = OUT / 8;
    size_t tid = (size_t)blockIdx.x * 256 + threadIdx.x;
    int d = (int)(tid / L);
    int p = (int)(tid % L);
    if (d >= n) return;
    int beg = ds[d];
    int end = ds[d + 1];
    int deg = end - beg;
    float acc[8] = {};
    int i = beg;
    for (; i + 2 <= end; i += 2) {
        f16x8 v0 = *(const f16x8*)(msg + (size_t)i * OUT + p * 8);
        f16x8 v1 = *(const f16x8*)(msg + (size_t)(i + 1) * OUT + p * 8);
#pragma unroll
        for (int j = 0; j < 8; ++j) acc[j] += (float)v0[j] + (float)v1[j];
    }
    if (i < end) {
        f16x8 v0 = *(const f16x8*)(msg + (size_t)i * OUT + p * 8);
#pragma unroll
        for (int j = 0; j < 8; ++j) acc[j] += (float)v0[j];
    }
    float sc = 1.f / (float)(deg + 1);
    f16x8 sv = *(const f16x8*)(xwa + (size_t)d * LDR + NC + p * 8);  // x*Wself
    float o[8];
    f16x8 oh;
#pragma unroll
    for (int j = 0; j < 8; ++j) {
        float v = acc[j] + (float)sv[j] * sc + bias[p * 8 + j];
        if (act) v = v > 0.f ? v : 0.1f * v;
        o[j] = v;
        oh[j] = (_Float16)v;
    }
    *(f16x8*)(outp + (size_t)d * ldo + col0 + p * 8) = oh;
    if (clust) {  // fused mean-pool accumulation (fp32, pre-quantization)
        float* pp = pooled + (size_t)clust[d] * OUT + p * 8;
#pragma unroll
        for (int j = 0; j < 8; ++j) unsafeAtomicAdd(&pp[j], o[j]);
    }
}

// ---------------- pooling divide ----------------
__global__ void pool_div(float* __restrict__ pooled, const int* __restrict__ pcnt, int C, int m)
{
    size_t tid = (size_t)blockIdx.x * 256 + threadIdx.x;
    int j = (int)(tid / C);
    if (j >= m) return;
    pooled[tid] /= fmaxf((float)pcnt[j], 1.f);
}

// ---------------- fc1 weight -> fp16 transposed [1024][32] ----------------
__global__ void w1_to_f16t(const float* __restrict__ w1, _Float16* __restrict__ w1t)
{
    int i = blockIdx.x * 256 + threadIdx.x;
    if (i >= 32 * 1024) return;
    int n = i >> 5, k = i & 31;
    w1t[i] = (_Float16)w1[k * 1024 + n];
}

// ---------------- fused FC head via f16 MFMA: lrelu(y@W1+b1)@W2+b2, row-normalize ----------------
__global__ __launch_bounds__(256) void fc_head2(
    const _Float16* __restrict__ yin, const _Float16* __restrict__ w1t,
    const float* __restrict__ b1, const float* __restrict__ w2,
    const float* __restrict__ b2, float* __restrict__ outp, int n)
{
    const int lane = threadIdx.x & 63, wv = threadIdx.x >> 6;
    const int g = lane >> 4, r16 = lane & 15;
    const int node0 = blockIdx.x * 64 + wv * 16;

    f16x8 afrag = {};
    int anode = node0 + r16;
    if (anode < n) afrag = *(const f16x8*)(yin + (size_t)anode * 32 + g * 8);

    float o0[4] = {0.f, 0.f, 0.f, 0.f};
    float o1[4] = {0.f, 0.f, 0.f, 0.f};
    float o2[4] = {0.f, 0.f, 0.f, 0.f};
    const f32x4 zero4 = {0.f, 0.f, 0.f, 0.f};

#pragma unroll 2
    for (int t = 0; t < 64; ++t) {
        const f16x8 bfrag = *(const f16x8*)(w1t + ((size_t)(t * 16 + r16)) * 32 + g * 8);
        f32x4 d = __builtin_amdgcn_mfma_f32_16x16x32_f16(afrag, bfrag, zero4, 0, 0, 0);
        int kh = t * 16 + r16;
        float b1v = b1[kh];
        float w20 = w2[kh * 3], w21 = w2[kh * 3 + 1], w22 = w2[kh * 3 + 2];
#pragma unroll
        for (int r = 0; r < 4; ++r) {
            float h = d[r] + b1v;
            h = h > 0.f ? h : 0.1f * h;
            o0[r] += h * w20;
            o1[r] += h * w21;
            o2[r] += h * w22;
        }
    }
#pragma unroll
    for (int r = 0; r < 4; ++r) {
#pragma unroll
        for (int off = 1; off < 16; off <<= 1) {
            o0[r] += __shfl_xor(o0[r], off);
            o1[r] += __shfl_xor(o1[r], off);
            o2[r] += __shfl_xor(o2[r], off);
        }
    }
    if (r16 == 0) {
#pragma unroll
        for (int r = 0; r < 4; ++r) {
            int node = node0 + g * 4 + r;
            if (node >= n) continue;
            float v0 = o0[r] + b2[0];
            float v1 = o1[r] + b2[1];
            float v2 = o2[r] + b2[2];
            float nr = fmaxf(sqrtf(v0 * v0 + v1 * v1 + v2 * v2), 1e-12f);
            outp[(size_t)node * 3 + 0] = v0 / nr;
            outp[(size_t)node * 3 + 1] = v1 / nr;
            outp[(size_t)node * 3 + 2] = v2 / nr;
        }
    }
}

// ---------------- dispatch helpers ----------------
static void launch_msg(int outC, const int* srcs, const int* dsts, int E,
                       const _Float16* xwa, const _Float16* xuh, const float* cvec,
                       const int* ds, int* curd, _Float16* msg, hipStream_t stream)
{
    dim3 g(ceil_div((size_t)E * (outC / 32), 256));
    if (outC == 32)       feast_msg<32><<<g, 256, 0, stream>>>(srcs, dsts, E, xwa, xuh, cvec, ds, curd, msg);
    else if (outC == 64)  feast_msg<64><<<g, 256, 0, stream>>>(srcs, dsts, E, xwa, xuh, cvec, ds, curd, msg);
    else                  feast_msg<128><<<g, 256, 0, stream>>>(srcs, dsts, E, xwa, xuh, cvec, ds, curd, msg);
}

static void launch_red(int outC, const int* ds,
                       const _Float16* msg, const _Float16* xwa, const float* bias,
                       _Float16* outp, int n, int ldo, int col0, int act,
                       const int* clust, float* pooled, hipStream_t stream)
{
    dim3 g(ceil_div((size_t)n * (outC / 8), 256));
    if (outC == 32)       feast_red<32><<<g, 256, 0, stream>>>(ds, msg, xwa, bias, outp, n, ldo, col0, act, clust, pooled);
    else if (outC == 64)  feast_red<64><<<g, 256, 0, stream>>>(ds, msg, xwa, bias, outp, n, ldo, col0, act, clust, pooled);
    else                  feast_red<128><<<g, 256, 0, stream>>>(ds, msg, xwa, bias, outp, n, ldo, col0, act, clust, pooled);
}

extern "C" void kernel_launch(void* const* d_in, const int* in_sizes, int n_in,
                              void* d_out, int out_size, void* d_ws, size_t ws_size,
                              hipStream_t stream)
{
    const float* x      = (const float*)d_in[0];
    const int*   ei1    = (const int*)d_in[1];
    const int*   ei2    = (const int*)d_in[2];
    const int*   ei3    = (const int*)d_in[3];
    const int*   clust2 = (const int*)d_in[4];
    const int*   clust3 = (const int*)d_in[5];
    const float* lp[8][4];
    for (int i = 0; i < 8; ++i)
        for (int j = 0; j < 4; ++j)
            lp[i][j] = (const float*)d_in[6 + i * 4 + j];  // l1..l4,r1..r4 x {u,c,w,b}
    const float* fc1_w = (const float*)d_in[38];
    const float* fc1_b = (const float*)d_in[39];
    const float* fc2_w = (const float*)d_in[40];
    const float* fc2_b = (const float*)d_in[41];
    float* out = (float*)d_out;

    static const int lK[8]   = {6, 32, 64, 128, 128, 128, 64, 64};
    static const int lOUT[8] = {32, 64, 128, 128, 64, 64, 32, 32};

    // ---- workspace layout (~210 MB) ----
    char* ws = (char*)d_ws;
    size_t off = 0;
    auto alloc = [&](size_t b) { size_t p = off; off += (b + 255) & ~(size_t)255; return p; };
    _Float16* XWA = (_Float16*)(ws + alloc((size_t)cN1 * 336 * 2));  // 67.2 MB (max n*LDR)
    _Float16* MSG = (_Float16*)(ws + alloc((size_t)cE1 * 32 * 2));   // 76.8 MB
    _Float16* XUH = (_Float16*)(ws + alloc((size_t)cN1 * QLD * 2));  // 3.2 MB
    // fp16 activations
    _Float16* X1CAT = (_Float16*)(ws + alloc((size_t)cN1 * 64 * 2)); // 12.8 MB
    _Float16* X2CAT = (_Float16*)(ws + alloc((size_t)cN2 * 128 * 2));// 6.4 MB
    _Float16* X2B   = (_Float16*)(ws + alloc((size_t)cN2 * 64 * 2)); // 3.2 MB
    _Float16* X3    = (_Float16*)(ws + alloc((size_t)cN3 * 128 * 2));// 1.6 MB
    _Float16* YB    = (_Float16*)(ws + alloc((size_t)cN1 * 32 * 2)); // 6.4 MB
    // fp32 pooled buffers (GEMM A inputs)
    float* GATH = (float*)(ws + alloc((size_t)cN2 * 32 * 4));        // 3.2 MB
    float* P3   = (float*)(ws + alloc((size_t)cN3 * 64 * 4));        // 1.6 MB
    int* SRCS1 = (int*)(ws + alloc((size_t)cE1 * 4));
    int* SRCS2 = (int*)(ws + alloc((size_t)cE2 * 4));
    int* SRCS3 = (int*)(ws + alloc((size_t)cE3 * 4));
    int* DSTS1 = (int*)(ws + alloc((size_t)cE1 * 4));
    int* DSTS2 = (int*)(ws + alloc((size_t)cE2 * 4));
    int* DSTS3 = (int*)(ws + alloc((size_t)cE3 * 4));
    // combined scan outputs per level: [doff(n) | soff+E(n)]; ds[n]=E acts as doff sentinel
    int* DS1 = (int*)(ws + alloc((size_t)2 * cN1 * 4));
    int* DS2 = (int*)(ws + alloc((size_t)2 * cN2 * 4));
    int* DS3 = (int*)(ws + alloc((size_t)2 * cN3 * 4));
    // zero-block, ONE memset: per level [dcnt|scnt|curs|curd] + PC2 + PC3
    size_t zn = (size_t)4 * (cN1 + cN2 + cN3) + cN2 + cN3;
    int* ZBLK = (int*)(ws + alloc(zn * 4));
    int* CB1 = ZBLK;
    int* CURS1 = CB1 + 2 * cN1;
    int* CURD1 = CURS1 + cN1;
    int* CB2 = CURD1 + cN1;
    int* CURS2 = CB2 + 2 * cN2;
    int* CURD2 = CURS2 + cN2;
    int* CB3 = CURD2 + cN2;
    int* CURS3 = CB3 + 2 * cN3;
    int* CURD3 = CURS3 + cN3;
    int* PC2 = CURD3 + cN3;
    int* PC3 = PC2 + cN2;
    int* PART = (int*)(ws + alloc(1024 * 4));
    _Float16* W1T = (_Float16*)(ws + alloc((size_t)32 * 1024 * 2));
    // pre-packed B panels
    PackArgs pa;
    int ptot = 0;
    for (int i = 0; i < 8; ++i) {
        pa.W[i] = lp[i][2]; pa.c[i] = lp[i][1]; pa.u[i] = lp[i][0];
        pa.K[i] = lK[i]; pa.OUT[i] = lOUT[i];
        pa.Kpad[i] = (lK[i] + 31) & ~31;
        pa.base[i] = ptot;
        ptot += (NH * lOUT[i] + lOUT[i] + NH) * pa.Kpad[i];
    }
    pa.total = ptot;
    _Float16* WT = (_Float16*)(ws + alloc((size_t)ptot * 2));

    auto run_scan = [&](const int* in, int* outp, int n) {
        int nb = (n + 1023) / 1024;
        scan1<<<nb, 1024, 0, stream>>>(in, outp, nb > 1 ? PART : nullptr, n);
        if (nb > 1) {
            scan1<<<1, 1024, 0, stream>>>(PART, PART, nullptr, nb);
            scan_add<<<nb, 1024, 0, stream>>>(outp, PART, n);
        }
    };

    // ---- zero all counters in ONE memset ----
    hipMemsetAsync(ZBLK, 0, zn * 4, stream);

    // ---- per-level build: fused counts, ONE combined scan, segment-fill, 4B scatter ----
    auto build = [&](const int* ei, int E, int n, int* cb, int* curs, int* ds,
                     int* srcs, int* dsts) {
        count_both<<<ceil_div(E, 256), 256, 0, stream>>>(ei, ei + E, E, cb + n, cb);
        run_scan(cb, ds, 2 * n);  // ds[0:n]=doff ; ds[n:2n]=soff+E (ds[n]=E sentinel)
        fill_src<<<ceil_div(n, 256), 256, 0, stream>>>(ds + n, cb + n, srcs, n, E);
        scatter_dst<<<ceil_div(E, 256), 256, 0, stream>>>(ei, ei + E, E, ds + n, curs, dsts, E);
    };
    build(ei1, cE1, cN1, CB1, CURS1, DS1, SRCS1, DSTS1);
    build(ei2, cE2, cN2, CB2, CURS2, DS2, SRCS2, DSTS2);
    build(ei3, cE3, cN3, CB3, CURS3, DS3, SRCS3, DSTS3);

    // ---- pack all B panels (W|Wself|u, transposed fp16) + fc1 transpose ----
    pack_b_all<<<ceil_div(ptot, 256), 256, 0, stream>>>(pa, WT);
    w1_to_f16t<<<ceil_div(32 * 1024, 256), 256, 0, stream>>>(fc1_w, W1T);

    auto feast = [&](auto* xin, int ldx, const int* ridx, int n, int cin, int li,
                     const int* srcs, const int* dsts, const int* ds, int* curd, int E,
                     _Float16* dstp, int ldo, int col0, int act,
                     const int* pclust, float* pooled) {
        int outC = lOUT[li];
        int NC = NH * outC;
        int N = NC + outC + NH;
        gemm_merged<<<dim3(ceil_div(N, 64), ceil_div(n, 64)), 256, 0, stream>>>(
            xin, ldx, ridx, WT + (size_t)pa.base[li], pa.Kpad[li], XWA, XUH, n, cin, NC, outC);
        launch_msg(outC, srcs, dsts, E, XWA, XUH, lp[li][1], ds, curd, MSG, stream);
        launch_red(outC, ds, MSG, XWA, lp[li][3], dstp, n, ldo, col0, act, pclust, pooled, stream);
    };

    // l1: [N1,6] -> [N1,32] into X1CAT[:, 0:32]  (+fused pool into GATH)
    hipMemsetAsync(GATH, 0, (size_t)cN2 * 32 * 4, stream);
    count_idx<<<ceil_div(cN1, 256), 256, 0, stream>>>(clust2, cN1, PC2);
    feast(x, 6, nullptr, cN1, 6, 0, SRCS1, DSTS1, DS1, CURD1, cE1, X1CAT, 64, 0, 1, clust2, GATH);
    pool_div<<<ceil_div((size_t)cN2 * 32, 256), 256, 0, stream>>>(GATH, PC2, 32, cN2);

    // l2: [N2,32] -> [N2,64] into X2CAT[:, 0:64]  (+fused pool into P3)
    count_idx<<<ceil_div(cN2, 256), 256, 0, stream>>>(clust3, cN2, PC3);
    hipMemsetAsync(P3, 0, (size_t)cN3 * 64 * 4, stream);
    feast(GATH, 32, nullptr, cN2, 32, 1, SRCS2, DSTS2, DS2, CURD2, cE2, X2CAT, 128, 0, 1, clust3, P3);
    pool_div<<<ceil_div((size_t)cN3 * 64, 256), 256, 0, stream>>>(P3, PC3, 64, cN3);

    // l3: [N3,64] -> [N3,128] into X3
    feast(P3, 64, nullptr, cN3, 64, 2, SRCS3, DSTS3, DS3, CURD3, cE3, X3, 128, 0, 1, nullptr, nullptr);
    // l4: [N3,128] -> [N3,128] in-place (X3 consumed by gemm before red writes)
    feast(X3, 128, nullptr, cN3, 128, 3, SRCS3, DSTS3, DS3, CURD3, cE3, X3, 128, 0, 1, nullptr, nullptr);

    // r1: feast over unpooled x3 (gather fused via ridx=clust3) -> X2CAT[:, 64:128] (no act)
    feast(X3, 128, clust3, cN2, 128, 4, SRCS2, DSTS2, DS2, CURD2, cE2, X2CAT, 128, 64, 0, nullptr, nullptr);

    // r2: [N2,128] -> [N2,64] into X2B
    feast(X2CAT, 128, nullptr, cN2, 128, 5, SRCS2, DSTS2, DS2, CURD2, cE2, X2B, 64, 0, 1, nullptr, nullptr);

    // r3: feast over unpooled x2 (gather fused via ridx=clust2) -> X1CAT[:, 32:64] (no act)
    feast(X2B, 64, clust2, cN1, 64, 6, SRCS1, DSTS1, DS1, CURD1, cE1, X1CAT, 64, 32, 0, nullptr, nullptr);

    // r4: [N1,64] -> [N1,32] into YB
    feast(X1CAT, 64, nullptr, cN1, 64, 7, SRCS1, DSTS1, DS1, CURD1, cE1, YB, 32, 0, 1, nullptr, nullptr);

    // fused FC head + normalize (f16 MFMA)
    fc_head2<<<ceil_div(cN1, 64), 256, 0, stream>>>(YB, W1T, fc1_b, fc2_w, fc2_b, out, cN1);

    (void)in_sizes; (void)n_in; (void)out_size; (void)ws_size;
}